// Round 1
// baseline (276.661 us; speedup 1.0000x reference)
//
#include <hip/hip_runtime.h>

#define B_  4
#define NT_ 1024
#define NS_ 1024
#define D_  1024
#define H_  16
#define HD_ 64

typedef unsigned short u16;
typedef __attribute__((ext_vector_type(8))) short short8;
typedef __attribute__((ext_vector_type(4))) float f32x4;
typedef __attribute__((ext_vector_type(4))) unsigned short u16x4;

static __device__ __forceinline__ u16 f2bf(float f) {
  unsigned u = __builtin_bit_cast(unsigned, f);
  u += 0x7fff + ((u >> 16) & 1);          // RNE
  return (u16)(u >> 16);
}

static __device__ __forceinline__ f32x4 mfma16(short8 a, short8 b, f32x4 c) {
  return __builtin_amdgcn_mfma_f32_16x16x32_bf16(a, b, c, 0, 0, 0);
}

#define GLDS16(g, l) __builtin_amdgcn_global_load_lds( \
    (const __attribute__((address_space(1))) void*)(g), \
    (__attribute__((address_space(3))) void*)(l), 16, 0, 0)

// ---------------------------------------------------------------- convert
struct CvtArgs {
  const float* src[7];
  u16* dst[7];
  int n[7];
};

__global__ __launch_bounds__(256) void cvt_kernel(CvtArgs a) {
  const int z = blockIdx.z;
  const float* __restrict__ src = a.src[z];
  u16* __restrict__ dst = a.dst[z];
  const int n = a.n[z];
  int i = (blockIdx.x * 256 + threadIdx.x) * 4;
  const int stride = gridDim.x * 256 * 4;
  for (; i < n; i += stride) {
    float4 v = *reinterpret_cast<const float4*>(src + i);
    u16x4 o;
    o[0] = f2bf(v.x); o[1] = f2bf(v.y); o[2] = f2bf(v.z); o[3] = f2bf(v.w);
    *reinterpret_cast<u16x4*>(dst + i) = o;
  }
}

// ---------------------------------------------------------------- GEMM (B^T form)
// C[i][j] = sum_k A[i][k]*Bt[j][k] + bias[j].  128x128 tile, BK=32, 4 waves.
template<bool OBF16>
static __device__ __forceinline__ void gemm_body(
    const u16* __restrict__ A, const u16* __restrict__ Bt,
    const float* __restrict__ bias, void* __restrict__ Cout,
    const int N, const int K) {
  __shared__ u16 sA[128 * 32];
  __shared__ u16 sB[128 * 32];
  const int tid = threadIdx.x;
  const int wave = tid >> 6, lane = tid & 63;
  const int l15 = lane & 15, lq = lane >> 4;
  const size_t m0 = (size_t)blockIdx.y * 128;
  const size_t n0 = (size_t)blockIdx.x * 128;
  const int wr = (wave >> 1) * 64, wc = (wave & 1) * 64;
  f32x4 acc[4][4];
#pragma unroll
  for (int m = 0; m < 4; ++m)
#pragma unroll
    for (int n = 0; n < 4; ++n) acc[m][n] = (f32x4){0.f, 0.f, 0.f, 0.f};

  const int srow = lane >> 2;          // 0..15 within 16-row chunk
  const int scol = (lane & 3) * 8;     // 0,8,16,24

  for (int kt = 0; kt < K; kt += 32) {
#pragma unroll
    for (int i = 0; i < 2; ++i) {
      const int q = wave * 2 + i;      // 0..7 : 16-row chunk of the tile
      const u16* ga = A + (m0 + q * 16 + srow) * K + kt + scol;
      const u16* gb = Bt + (n0 + q * 16 + srow) * K + kt + scol;
      GLDS16(ga, sA + q * 512);
      GLDS16(gb, sB + q * 512);
    }
    __syncthreads();                   // drains vmcnt (global_load_lds) too
    short8 af[4], bfr[4];
#pragma unroll
    for (int m = 0; m < 4; ++m)
      af[m] = *reinterpret_cast<const short8*>(sA + (wr + m * 16 + l15) * 32 + lq * 8);
#pragma unroll
    for (int n = 0; n < 4; ++n)
      bfr[n] = *reinterpret_cast<const short8*>(sB + (wc + n * 16 + l15) * 32 + lq * 8);
#pragma unroll
    for (int m = 0; m < 4; ++m)
#pragma unroll
      for (int n = 0; n < 4; ++n)
        acc[m][n] = mfma16(af[m], bfr[n], acc[m][n]);
    __syncthreads();
  }
  // epilogue: C/D layout col=lane&15, row=(lane>>4)*4+r
#pragma unroll
  for (int m = 0; m < 4; ++m) {
    const size_t row0 = m0 + wr + m * 16 + lq * 4;
#pragma unroll
    for (int n = 0; n < 4; ++n) {
      const size_t col = n0 + wc + n * 16 + l15;
      const float bv = bias[col];
#pragma unroll
      for (int r = 0; r < 4; ++r) {
        const float v = acc[m][n][r] + bv;
        if (OBF16)
          ((u16*)Cout)[(row0 + r) * N + col] = f2bf(v);
        else
          ((float*)Cout)[(row0 + r) * N + col] = v;
      }
    }
  }
}

__global__ __launch_bounds__(256) void qkv_gemm_kernel(
    const u16* qb, const u16* kb, const u16* vb,
    const u16* wq, const u16* wk, const u16* wv,
    const float* bq, const float* bk, const float* bv,
    u16* qp, u16* kp, u16* vp) {
  const int z = blockIdx.z;
  const u16* A = (z == 0) ? qb : (z == 1) ? kb : vb;
  const u16* Bt = (z == 0) ? wq : (z == 1) ? wk : wv;
  const float* bias = (z == 0) ? bq : (z == 1) ? bk : bv;
  u16* C = (z == 0) ? qp : (z == 1) ? kp : vp;
  gemm_body<true>(A, Bt, bias, (void*)C, D_, D_);
}

__global__ __launch_bounds__(256) void oproj_kernel(
    const u16* __restrict__ A, const u16* __restrict__ Bt,
    const float* __restrict__ bias, float* __restrict__ C) {
  gemm_body<false>(A, Bt, bias, (void*)C, D_, D_);
}

// ---------------------------------------------------------------- V transpose
// vp [B, NS, D] -> vpT [B, H, HD, NS]
__global__ __launch_bounds__(256) void vtrans_kernel(const u16* __restrict__ vp,
                                                     u16* __restrict__ vpT) {
  __shared__ u16 t_lds[64][64];
  const int s0 = blockIdx.x * 64;
  const int h = blockIdx.y, b = blockIdx.z;
  const int tid = threadIdx.x;
  const int ri = tid >> 2;            // 0..63
  const int c0 = (tid & 3) * 16;      // 0,16,32,48
  const u16* src = vp + ((size_t)(b * NS_ + s0 + ri)) * D_ + h * HD_ + c0;
  *reinterpret_cast<short8*>(&t_lds[ri][c0]) = *reinterpret_cast<const short8*>(src);
  *reinterpret_cast<short8*>(&t_lds[ri][c0 + 8]) = *reinterpret_cast<const short8*>(src + 8);
  __syncthreads();
  short8 o1, o2;
#pragma unroll
  for (int j = 0; j < 8; ++j) o1[j] = (short)t_lds[c0 + j][ri];
#pragma unroll
  for (int j = 0; j < 8; ++j) o2[j] = (short)t_lds[c0 + 8 + j][ri];
  u16* dst = vpT + ((size_t)((b * H_ + h) * HD_ + ri)) * NS_ + s0 + c0;
  *reinterpret_cast<short8*>(dst) = o1;
  *reinterpret_cast<short8*>(dst + 8) = o2;
}

// ---------------------------------------------------------------- fused attention
// Per block: (qtile of 32 rows, h, b).  8 waves, wave w owns score cols [w*128,(w+1)*128).
// Scores stay in registers; P (bf16, XOR-swizzled) aliases reduction scratch in 64KB LDS.
__global__ __launch_bounds__(512) void attn_kernel(
    const u16* __restrict__ qp, const u16* __restrict__ kp,
    const u16* __restrict__ vpT, const float* __restrict__ mask,
    float* __restrict__ wout, u16* __restrict__ ctx) {
  __shared__ float4 smem16[4096];       // 64KB, 16B aligned
  char* smem = (char*)smem16;
  float* red_max = (float*)smem;              // [32][8]
  float* red_sum = (float*)(smem + 1024);     // [32][8]
  float* rfin_max = (float*)(smem + 2048);    // [32]
  float* rfin_sinv = (float*)(smem + 2176);   // [32]
  char* P = smem;                             // [32][1024] bf16 swizzled (aliases scratch)

  const int qt = blockIdx.x, h = blockIdx.y, b = blockIdx.z;
  const int tid = threadIdx.x, wave = tid >> 6, lane = tid & 63;
  const int l15 = lane & 15, lq = lane >> 4;
  const int wcb = wave * 128;

  // Q fragments (rows qt*32 + m*16 + l15, k = d)
  short8 qa[2][2];
  const u16* qbase = qp + ((size_t)(b * NT_ + qt * 32)) * D_ + h * HD_;
#pragma unroll
  for (int m = 0; m < 2; ++m)
#pragma unroll
    for (int ks = 0; ks < 2; ++ks)
      qa[m][ks] = *reinterpret_cast<const short8*>(
          qbase + (size_t)(m * 16 + l15) * D_ + ks * 32 + lq * 8);

  f32x4 acc[2][8];
#pragma unroll
  for (int m = 0; m < 2; ++m)
#pragma unroll
    for (int c = 0; c < 8; ++c) acc[m][c] = (f32x4){0.f, 0.f, 0.f, 0.f};

  const u16* kbase = kp + ((size_t)b * NS_) * D_ + h * HD_ + lq * 8;
#pragma unroll
  for (int c = 0; c < 8; ++c) {
    const size_t sb = wcb + c * 16 + l15;
#pragma unroll
    for (int ks = 0; ks < 2; ++ks) {
      short8 kf = *reinterpret_cast<const short8*>(kbase + sb * D_ + ks * 32);
      acc[0][c] = mfma16(qa[0][ks], kf, acc[0][c]);
      acc[1][c] = mfma16(qa[1][ks], kf, acc[1][c]);
    }
  }

  // scale + mask (C/D layout: col=l15, row=lq*4+r within 16)
  const float* mbase = mask + (size_t)(qt * 32) * NS_;
#pragma unroll
  for (int m = 0; m < 2; ++m)
#pragma unroll
    for (int r = 0; r < 4; ++r) {
      const int t_loc = m * 16 + lq * 4 + r;
#pragma unroll
      for (int c = 0; c < 8; ++c) {
        const int s = wcb + c * 16 + l15;
        acc[m][c][r] = acc[m][c][r] * 0.125f + mbase[(size_t)t_loc * NS_ + s];
      }
    }

  // row max: in-lane over c, then across the 16-lane col group
#pragma unroll
  for (int m = 0; m < 2; ++m)
#pragma unroll
    for (int r = 0; r < 4; ++r) {
      float v = acc[m][0][r];
#pragma unroll
      for (int c = 1; c < 8; ++c) v = fmaxf(v, acc[m][c][r]);
      v = fmaxf(v, __shfl_xor(v, 1));
      v = fmaxf(v, __shfl_xor(v, 2));
      v = fmaxf(v, __shfl_xor(v, 4));
      v = fmaxf(v, __shfl_xor(v, 8));
      if (l15 == 0) red_max[(m * 16 + lq * 4 + r) * 8 + wave] = v;
    }
  __syncthreads();
  if (tid < 32) {
    float v = red_max[tid * 8];
#pragma unroll
    for (int w = 1; w < 8; ++w) v = fmaxf(v, red_max[tid * 8 + w]);
    rfin_max[tid] = v;
  }
  __syncthreads();

  // exp + row sum
#pragma unroll
  for (int m = 0; m < 2; ++m)
#pragma unroll
    for (int r = 0; r < 4; ++r) {
      const int t_loc = m * 16 + lq * 4 + r;
      const float mx = rfin_max[t_loc];
      float sum = 0.f;
#pragma unroll
      for (int c = 0; c < 8; ++c) {
        const float e = __expf(acc[m][c][r] - mx);
        acc[m][c][r] = e;
        sum += e;
      }
      sum += __shfl_xor(sum, 1);
      sum += __shfl_xor(sum, 2);
      sum += __shfl_xor(sum, 4);
      sum += __shfl_xor(sum, 8);
      if (l15 == 0) red_sum[t_loc * 8 + wave] = sum;
    }
  __syncthreads();
  if (tid < 32) {
    float s = 0.f;
#pragma unroll
    for (int w = 0; w < 8; ++w) s += red_sum[tid * 8 + w];
    rfin_sinv[tid] = 1.0f / s;
  }
  __syncthreads();

  // pull reciprocal sums into registers, then free the scratch region for P
  float rinv_reg[2][4];
#pragma unroll
  for (int m = 0; m < 2; ++m)
#pragma unroll
    for (int r = 0; r < 4; ++r) rinv_reg[m][r] = rfin_sinv[m * 16 + lq * 4 + r];
  __syncthreads();

  // write normalized weights (f32, global) + P (bf16, LDS, swizzled)
  float* wbase = wout + ((size_t)((b * H_ + h) * NT_ + qt * 32)) * NS_;
#pragma unroll
  for (int m = 0; m < 2; ++m)
#pragma unroll
    for (int r = 0; r < 4; ++r) {
      const int t_loc = m * 16 + lq * 4 + r;
      const float rinv = rinv_reg[m][r];
      float* wrow = wbase + (size_t)t_loc * NS_;
      char* prow = P + t_loc * 2048;
      const int swz = (t_loc & 7) << 4;
#pragma unroll
      for (int c = 0; c < 8; ++c) {
        const int s = wcb + c * 16 + l15;
        const float w = acc[m][c][r] * rinv;
        wrow[s] = w;
        *reinterpret_cast<u16*>(prow + ((s * 2) ^ swz)) = f2bf(w);
      }
    }
  __syncthreads();

  // Phase B: ctx[32][64] = P @ V.  wave -> (t-half, d-quarter)
  const int th = wave >> 2, dq = wave & 3;
  f32x4 acc2 = (f32x4){0.f, 0.f, 0.f, 0.f};
  const int t = th * 16 + l15;
  const char* pr = P + t * 2048;
  const int swz2 = (t & 7) << 4;
  const u16* vbase = vpT + ((size_t)((b * H_ + h) * HD_ + dq * 16 + l15)) * NS_ + lq * 8;
#pragma unroll 4
  for (int ks = 0; ks < 32; ++ks) {
    const int sk2 = (ks * 32 + lq * 8) * 2;
    short8 pa = *reinterpret_cast<const short8*>(pr + (sk2 ^ swz2));
    short8 vf = *reinterpret_cast<const short8*>(vbase + ks * 32);
    acc2 = mfma16(pa, vf, acc2);
  }
  u16* cbase = ctx + ((size_t)(b * NT_ + qt * 32 + th * 16 + lq * 4)) * D_ + h * HD_ + dq * 16 + l15;
#pragma unroll
  for (int r = 0; r < 4; ++r) cbase[(size_t)r * D_] = f2bf(acc2[r]);
}

// ---------------------------------------------------------------- launch
extern "C" void kernel_launch(void* const* d_in, const int* in_sizes, int n_in,
                              void* d_out, int out_size, void* d_ws, size_t ws_size,
                              hipStream_t stream) {
  const float* q   = (const float*)d_in[0];
  const float* k   = (const float*)d_in[1];
  const float* v   = (const float*)d_in[2];
  const float* q_w = (const float*)d_in[3];
  const float* k_w = (const float*)d_in[4];
  const float* v_w = (const float*)d_in[5];
  const float* o_w = (const float*)d_in[6];
  const float* b_q = (const float*)d_in[7];
  const float* b_k = (const float*)d_in[8];
  const float* b_v = (const float*)d_in[9];
  const float* b_o = (const float*)d_in[10];
  const float* msk = (const float*)d_in[11];

  float* out = (float*)d_out;                       // [B,NT,D]
  float* wout = out + (size_t)B_ * NT_ * D_;        // [B,H,NT,NS]

  // workspace layout (bf16 elements)
  u16* qb = (u16*)d_ws;            // 4M   @0
  u16* kb = qb + 4194304;          //      @8MB
  u16* vb = kb + 4194304;          //      @16MB
  u16* wq = vb + 4194304;          // 1M   @24MB
  u16* wk = wq + 1048576;          //      @26MB
  u16* wv = wk + 1048576;          //      @28MB
  u16* wo = wv + 1048576;          //      @30MB
  u16* qp = wo + 1048576;          // 4M   @32MB
  u16* kp = qp + 4194304;          //      @40MB
  u16* vp = kp + 4194304;          //      @48MB  (total 56MB)
  u16* vpT = qb;                   // reuse: q bf16 dead after projections
  u16* ctx = kb;                   // reuse: k bf16 dead after projections

  CvtArgs ca;
  ca.src[0] = q;   ca.dst[0] = qb; ca.n[0] = B_ * NT_ * D_;
  ca.src[1] = k;   ca.dst[1] = kb; ca.n[1] = B_ * NS_ * D_;
  ca.src[2] = v;   ca.dst[2] = vb; ca.n[2] = B_ * NS_ * D_;
  ca.src[3] = q_w; ca.dst[3] = wq; ca.n[3] = D_ * D_;
  ca.src[4] = k_w; ca.dst[4] = wk; ca.n[4] = D_ * D_;
  ca.src[5] = v_w; ca.dst[5] = wv; ca.n[5] = D_ * D_;
  ca.src[6] = o_w; ca.dst[6] = wo; ca.n[6] = D_ * D_;
  cvt_kernel<<<dim3(256, 1, 7), 256, 0, stream>>>(ca);

  qkv_gemm_kernel<<<dim3(8, 32, 3), 256, 0, stream>>>(
      qb, kb, vb, wq, wk, wv, b_q, b_k, b_v, qp, kp, vp);

  vtrans_kernel<<<dim3(16, 16, 4), 256, 0, stream>>>(vp, vpT);

  attn_kernel<<<dim3(32, 16, 4), 512, 0, stream>>>(qp, kp, vpT, msk, wout, ctx);

  oproj_kernel<<<dim3(8, 32), 256, 0, stream>>>(ctx, wo, b_o, out);
}